// Round 1
// baseline (13102.765 us; speedup 1.0000x reference)
//
#include <hip/hip_runtime.h>
#include <math.h>
#include <stdint.h>

#define TT 500
#define BB 16
#define B2 32
#define FF 240
#define HH 512
#define G2 1024
#define MROWS (TT*B2)   // 16000

// ---------------- zero counters ----------------
__global__ void zero_cnt(unsigned int* cnt) {
    cnt[blockIdx.x * 256 + threadIdx.x] = 0u;
}

// ---------------- GEMM: w[m,g] = sum_k A[m,k] * Ww[g,k] ----------------
// LAYER 0: A = x (B,T,F) with x2 gather, K=240.
// LAYER 1: A = hist0 (T,B2,H) with y0/x2 gather, K=1024.
template<int LAYER>
__global__ __launch_bounds__(256)
void gemm_kernel(const float* __restrict__ A_src, const float* __restrict__ Bmat,
                 float* __restrict__ C)
{
    constexpr int K = (LAYER == 0) ? 240 : 1024;
    __shared__ float As[16][65];
    __shared__ float Bs[16][65];
    const int tid = threadIdx.x;
    const int m0 = blockIdx.x * 64;
    const int n0 = blockIdx.y * 64;
    const int lm = tid >> 2;          // 0..63 tile row (for loads)
    const int kq = (tid & 3) * 4;     // 0,4,8,12
    const int tm = (tid & 15) * 4;    // compute micro-tile
    const int tn = (tid >> 4) * 4;
    float acc[4][4] = {};
    const int m = m0 + lm;
    const int t = m >> 5;
    const int b2 = m & 31;

    for (int k0 = 0; k0 < K; k0 += 16) {
        const int k = k0 + kq;
        float4 av, bv;
        if (LAYER == 0) {
            const float* p = (b2 < 16)
                ? (A_src + ((size_t)(b2 * TT + t)) * FF + k)
                : (A_src + ((size_t)((b2 - 16) * TT + (TT - 1 - t))) * FF + k);
            av = *(const float4*)p;
        } else {
            const int selt = (b2 < 16) ? t : (TT - 1 - t);
            const int ot   = (b2 < 16) ? (TT - 1 - t) : t;
            const float* p = (k < HH)
                ? (A_src + ((size_t)(selt * B2 + (b2 & 15))) * HH + k)
                : (A_src + ((size_t)(ot * B2 + (b2 & 15) + 16)) * HH + (k - HH));
            av = *(const float4*)p;
        }
        bv = *(const float4*)(Bmat + (size_t)(n0 + lm) * K + k);
        As[kq + 0][lm] = av.x; As[kq + 1][lm] = av.y; As[kq + 2][lm] = av.z; As[kq + 3][lm] = av.w;
        Bs[kq + 0][lm] = bv.x; Bs[kq + 1][lm] = bv.y; Bs[kq + 2][lm] = bv.z; Bs[kq + 3][lm] = bv.w;
        __syncthreads();
        #pragma unroll
        for (int kk = 0; kk < 16; ++kk) {
            float a[4], b[4];
            #pragma unroll
            for (int i = 0; i < 4; ++i) { a[i] = As[kk][tm + i]; b[i] = Bs[kk][tn + i]; }
            #pragma unroll
            for (int i = 0; i < 4; ++i)
                #pragma unroll
                for (int j = 0; j < 4; ++j) acc[i][j] += a[i] * b[j];
        }
        __syncthreads();
    }
    #pragma unroll
    for (int i = 0; i < 4; ++i)
        #pragma unroll
        for (int j = 0; j < 4; ++j)
            C[(size_t)(m0 + tm + i) * G2 + (n0 + tn + j)] = acc[i][j];
}

// ---------------- BatchNorm stats ----------------
__global__ __launch_bounds__(256)
void stats_partial(const float* __restrict__ w, float* __restrict__ partS,
                   float* __restrict__ partQ)
{
    const int col = blockIdx.x * 256 + threadIdx.x;
    const int row0 = blockIdx.y * 128;
    float s = 0.f, q = 0.f;
    for (int r = 0; r < 128; ++r) {
        float v = w[(size_t)(row0 + r) * G2 + col];
        s += v; q += v * v;
    }
    partS[blockIdx.y * G2 + col] = s;
    partQ[blockIdx.y * G2 + col] = q;
}

__global__ __launch_bounds__(256)
void stats_final(const float* __restrict__ partS, const float* __restrict__ partQ,
                 const float* __restrict__ gamma, const float* __restrict__ beta,
                 float* __restrict__ scale, float* __restrict__ shift)
{
    const int col = blockIdx.x * 256 + threadIdx.x;
    float s = 0.f, q = 0.f;
    for (int i = 0; i < 125; ++i) { s += partS[i * G2 + col]; q += partQ[i * G2 + col]; }
    const float mean = s * (1.f / 16000.f);
    float var = q * (1.f / 16000.f) - mean * mean;
    var = fmaxf(var, 0.f);
    const float sc = gamma[col] * rsqrtf(var + 1e-5f);
    scale[col] = sc;
    shift[col] = beta[col] - mean * sc;
}

// ---------------- persistent recurrence ----------------
// 32 workgroups x 512 threads. Workgroup g owns j in [16g,16g+16).
// Gate rows: a-row = 16g+jj, z-row = 512+16g+jj. Weights in registers,
// k-split: thread(jj=tid&15, kc=tid>>4) holds Wu[row, kc*16 .. +16].
#define REC_LDS_FLOATS (B2*HH + 2*8*16*33)

__global__ __launch_bounds__(512)
void rec_kernel(const float* __restrict__ w, const float* __restrict__ scale,
                const float* __restrict__ shift, const float* __restrict__ Wu,
                float* __restrict__ hist, unsigned int* cnt)
{
    extern __shared__ float lds[];
    float* h_lds = lds;                       // 32*512
    float* reda  = lds + B2 * HH;             // 8*16*33
    float* redz  = reda + 8 * 16 * 33;        // 8*16*33

    const int g   = blockIdx.x;
    const int tid = threadIdx.x;
    const int jj  = tid & 15;
    const int kc  = tid >> 4;       // 0..31  (doubles as batch index for update phase)
    const int wv  = tid >> 6;       // wave 0..7

    // weight registers
    float wa[16], wz[16];
    {
        const int arow = 16 * g + jj, zrow = HH + 16 * g + jj;
        #pragma unroll
        for (int i = 0; i < 16; ++i) {
            wa[i] = Wu[(size_t)arow * HH + kc * 16 + i];
            wz[i] = Wu[(size_t)zrow * HH + kc * 16 + i];
        }
    }
    // update-phase mapping: thread -> (batch ub, gate ujj)
    const int ub = kc, ujj = jj;
    const float scl_a = scale[16 * g + ujj],      sh_a = shift[16 * g + ujj];
    const float scl_z = scale[HH + 16 * g + ujj], sh_z = shift[HH + 16 * g + ujj];

    for (int i = tid; i < B2 * HH; i += 512) h_lds[i] = 0.f;
    __syncthreads();

    for (int t = 0; t < TT; ++t) {
        if (t > 0) {
            if (tid == 0) {
                while (__hip_atomic_load(&cnt[t - 1], __ATOMIC_RELAXED,
                                         __HIP_MEMORY_SCOPE_AGENT) < 32u)
                    __builtin_amdgcn_s_sleep(2);
                __builtin_amdgcn_fence(__ATOMIC_ACQUIRE, "agent");
            }
            __syncthreads();
            const float4* src = (const float4*)(hist + (size_t)(t - 1) * B2 * HH);
            float4* dst = (float4*)h_lds;
            #pragma unroll
            for (int r = 0; r < 8; ++r) dst[tid + 512 * r] = src[tid + 512 * r];
            __syncthreads();
        }
        // raw w terms for this thread's (ub, ujj)
        const float wra = w[((size_t)t * B2 + ub) * G2 + 16 * g + ujj];
        const float wrz = w[((size_t)t * B2 + ub) * G2 + HH + 16 * g + ujj];

        // partial dots over this thread's 16-wide k-chunk, all 32 batches
        float pa[32], pz[32];
        #pragma unroll
        for (int b = 0; b < 32; ++b) {
            const float4* hp4 = (const float4*)&h_lds[b * HH + kc * 16];
            float hv[16];
            *(float4*)&hv[0]  = hp4[0];
            *(float4*)&hv[4]  = hp4[1];
            *(float4*)&hv[8]  = hp4[2];
            *(float4*)&hv[12] = hp4[3];
            float a0 = 0.f, z0 = 0.f;
            #pragma unroll
            for (int i = 0; i < 16; ++i) { a0 += wa[i] * hv[i]; z0 += wz[i] * hv[i]; }
            pa[b] = a0; pz[b] = z0;
        }
        // reduce kc strata within wave (lanes xor 16, 32)
        #pragma unroll
        for (int b = 0; b < 32; ++b) {
            pa[b] += __shfl_xor(pa[b], 16); pa[b] += __shfl_xor(pa[b], 32);
            pz[b] += __shfl_xor(pz[b], 16); pz[b] += __shfl_xor(pz[b], 32);
        }
        if ((tid & 63) < 16) {
            #pragma unroll
            for (int b = 0; b < 32; ++b) {
                reda[(wv * 16 + jj) * 33 + b] = pa[b];
                redz[(wv * 16 + jj) * 33 + b] = pz[b];
            }
        }
        __syncthreads();
        // final cross-wave sum + gate math for (ub, ujj)
        float asum = 0.f, zsum = 0.f;
        #pragma unroll
        for (int w8 = 0; w8 < 8; ++w8) {
            asum += reda[(w8 * 16 + ujj) * 33 + ub];
            zsum += redz[(w8 * 16 + ujj) * 33 + ub];
        }
        const float aval = scl_a * wra + sh_a + asum;
        const float zval = scl_z * wrz + sh_z + zsum;
        const float zt = 1.f / (1.f + __expf(-zval));
        const float hold = h_lds[ub * HH + 16 * g + ujj];
        const float hn = zt * hold + (1.f - zt) * fmaxf(aval, 0.f);
        hist[((size_t)t * B2 + ub) * HH + 16 * g + ujj] = hn;
        __syncthreads();   // drains vmcnt: all stores of this wg complete
        if (tid == 0) {
            __builtin_amdgcn_fence(__ATOMIC_RELEASE, "agent");
            __hip_atomic_fetch_add(&cnt[t], 1u, __ATOMIC_RELAXED,
                                   __HIP_MEMORY_SCOPE_AGENT);
        }
    }
}

// ---------------- final transpose: hist1 -> out (B,T,2H) ----------------
__global__ __launch_bounds__(256)
void out_kernel(const float* __restrict__ hist1, float* __restrict__ out)
{
    const int fi = blockIdx.x * 256 + threadIdx.x;   // float4 index
    const int flat = fi * 4;
    const int b = flat / (TT * G2);
    const int rem = flat - b * (TT * G2);
    const int t = rem >> 10;
    const int g = rem & 1023;
    float4 v;
    if (g < HH)
        v = *(const float4*)(hist1 + ((size_t)(t * B2 + b)) * HH + g);
    else
        v = *(const float4*)(hist1 + ((size_t)((TT - 1 - t) * B2 + b + 16)) * HH + (g - HH));
    *(float4*)(out + flat) = v;
}

extern "C" void kernel_launch(void* const* d_in, const int* in_sizes, int n_in,
                              void* d_out, int out_size, void* d_ws, size_t ws_size,
                              hipStream_t stream)
{
    const float* x   = (const float*)d_in[0];
    const float* Ww0 = (const float*)d_in[1];
    const float* Wu0 = (const float*)d_in[2];
    const float* g0  = (const float*)d_in[3];
    const float* b0  = (const float*)d_in[4];
    const float* Ww1 = (const float*)d_in[5];
    const float* Wu1 = (const float*)d_in[6];
    const float* g1  = (const float*)d_in[7];
    const float* b1  = (const float*)d_in[8];
    float* out = (float*)d_out;

    float* w     = (float*)d_ws;                         // 16000*1024
    float* hist0 = w + (size_t)MROWS * G2;               // 500*32*512
    float* hist1 = hist0 + (size_t)TT * B2 * HH;
    float* partS = hist1 + (size_t)TT * B2 * HH;         // 125*1024
    float* partQ = partS + 125 * G2;
    float* scale = partQ + 125 * G2;                     // 1024
    float* shift = scale + G2;
    unsigned int* cnt = (unsigned int*)(shift + G2);     // 1024 uints

    const size_t needed = ((size_t)MROWS * G2 + 2 * (size_t)TT * B2 * HH +
                           2 * 125 * G2 + 2 * G2) * 4 + 4096;
    if (ws_size < needed) return;  // fail loudly via wrong output rather than OOB

    const int rec_lds = REC_LDS_FLOATS * 4;
    hipFuncSetAttribute(reinterpret_cast<const void*>(rec_kernel),
                        hipFuncAttributeMaxDynamicSharedMemorySize, rec_lds);

    zero_cnt<<<4, 256, 0, stream>>>(cnt);

    // layer 0
    gemm_kernel<0><<<dim3(250, 16), 256, 0, stream>>>(x, Ww0, w);
    stats_partial<<<dim3(4, 125), 256, 0, stream>>>(w, partS, partQ);
    stats_final<<<4, 256, 0, stream>>>(partS, partQ, g0, b0, scale, shift);
    rec_kernel<<<32, 512, rec_lds, stream>>>(w, scale, shift, Wu0, hist0, cnt);

    // layer 1
    gemm_kernel<1><<<dim3(250, 16), 256, 0, stream>>>(hist0, Ww1, w);
    stats_partial<<<dim3(4, 125), 256, 0, stream>>>(w, partS, partQ);
    stats_final<<<4, 256, 0, stream>>>(partS, partQ, g1, b1, scale, shift);
    rec_kernel<<<32, 512, rec_lds, stream>>>(w, scale, shift, Wu1, hist1, cnt + 512);

    out_kernel<<<8000, 256, 0, stream>>>(hist1, out);
}

// Round 2
// 3674.054 us; speedup vs baseline: 3.5663x; 3.5663x over previous
//
#include <hip/hip_runtime.h>
#include <math.h>
#include <stdint.h>

#define TT 500
#define BB 16
#define B2 32
#define FF 240
#define HH 512
#define G2 1024
#define MROWS (TT*B2)   // 16000
#define REC_WGS 8

typedef __attribute__((ext_vector_type(8))) short bf16x8;
typedef __attribute__((ext_vector_type(4))) short bf16x4;
typedef __attribute__((ext_vector_type(4))) float f32x4;

static __device__ __forceinline__ unsigned short f2bf(float f) {
    union { float f; unsigned u; } v; v.f = f;
    unsigned r = v.u + 0x7FFFu + ((v.u >> 16) & 1u);
    return (unsigned short)(r >> 16);
}

// ---------------- zero counters ----------------
__global__ void zero_cnt(unsigned int* cnt) {
    cnt[blockIdx.x * 256 + threadIdx.x] = 0u;
}

// ---------------- GEMM: w[m,g] = sum_k A[m,k] * Ww[g,k] ----------------
template<int LAYER>
__global__ __launch_bounds__(256)
void gemm_kernel(const float* __restrict__ A_src, const float* __restrict__ Bmat,
                 float* __restrict__ C)
{
    constexpr int K = (LAYER == 0) ? 240 : 1024;
    __shared__ float As[16][65];
    __shared__ float Bs[16][65];
    const int tid = threadIdx.x;
    const int m0 = blockIdx.x * 64;
    const int n0 = blockIdx.y * 64;
    const int lm = tid >> 2;          // 0..63 tile row (for loads)
    const int kq = (tid & 3) * 4;     // 0,4,8,12
    const int tm = (tid & 15) * 4;    // compute micro-tile
    const int tn = (tid >> 4) * 4;
    float acc[4][4] = {};
    const int m = m0 + lm;
    const int t = m >> 5;
    const int b2 = m & 31;

    for (int k0 = 0; k0 < K; k0 += 16) {
        const int k = k0 + kq;
        float4 av, bv;
        if (LAYER == 0) {
            const float* p = (b2 < 16)
                ? (A_src + ((size_t)(b2 * TT + t)) * FF + k)
                : (A_src + ((size_t)((b2 - 16) * TT + (TT - 1 - t))) * FF + k);
            av = *(const float4*)p;
        } else {
            const int selt = (b2 < 16) ? t : (TT - 1 - t);
            const int ot   = (b2 < 16) ? (TT - 1 - t) : t;
            const float* p = (k < HH)
                ? (A_src + ((size_t)(selt * B2 + (b2 & 15))) * HH + k)
                : (A_src + ((size_t)(ot * B2 + (b2 & 15) + 16)) * HH + (k - HH));
            av = *(const float4*)p;
        }
        bv = *(const float4*)(Bmat + (size_t)(n0 + lm) * K + k);
        As[kq + 0][lm] = av.x; As[kq + 1][lm] = av.y; As[kq + 2][lm] = av.z; As[kq + 3][lm] = av.w;
        Bs[kq + 0][lm] = bv.x; Bs[kq + 1][lm] = bv.y; Bs[kq + 2][lm] = bv.z; Bs[kq + 3][lm] = bv.w;
        __syncthreads();
        #pragma unroll
        for (int kk = 0; kk < 16; ++kk) {
            float a[4], b[4];
            #pragma unroll
            for (int i = 0; i < 4; ++i) { a[i] = As[kk][tm + i]; b[i] = Bs[kk][tn + i]; }
            #pragma unroll
            for (int i = 0; i < 4; ++i)
                #pragma unroll
                for (int j = 0; j < 4; ++j) acc[i][j] += a[i] * b[j];
        }
        __syncthreads();
    }
    #pragma unroll
    for (int i = 0; i < 4; ++i)
        #pragma unroll
        for (int j = 0; j < 4; ++j)
            C[(size_t)(m0 + tm + i) * G2 + (n0 + tn + j)] = acc[i][j];
}

// ---------------- BatchNorm stats ----------------
__global__ __launch_bounds__(256)
void stats_partial(const float* __restrict__ w, float* __restrict__ partS,
                   float* __restrict__ partQ)
{
    const int col = blockIdx.x * 256 + threadIdx.x;
    const int row0 = blockIdx.y * 128;
    float s = 0.f, q = 0.f;
    for (int r = 0; r < 128; ++r) {
        float v = w[(size_t)(row0 + r) * G2 + col];
        s += v; q += v * v;
    }
    partS[blockIdx.y * G2 + col] = s;
    partQ[blockIdx.y * G2 + col] = q;
}

__global__ __launch_bounds__(256)
void stats_final(const float* __restrict__ partS, const float* __restrict__ partQ,
                 const float* __restrict__ gamma, const float* __restrict__ beta,
                 float* __restrict__ scale, float* __restrict__ shift)
{
    const int col = blockIdx.x * 256 + threadIdx.x;
    float s = 0.f, q = 0.f;
    for (int i = 0; i < 125; ++i) { s += partS[i * G2 + col]; q += partQ[i * G2 + col]; }
    const float mean = s * (1.f / 16000.f);
    float var = q * (1.f / 16000.f) - mean * mean;
    var = fmaxf(var, 0.f);
    const float sc = gamma[col] * rsqrtf(var + 1e-5f);
    scale[col] = sc;
    shift[col] = beta[col] - mean * sc;
}

// ---------------- persistent MFMA recurrence ----------------
// 8 WGs x 512 threads (8 waves). Wave wv: col-tile c = 4*g + (wv>>1),
// batch-half m = wv&1. Each wave computes the 16x16 a-tile and z-tile for
// (batches m*16..m*16+16) x (h-cols 16c..16c+16), K=512 in 16 MFMA k-steps.
// Wu held in registers as bf16 B-fragments (2 gates x 16 ksteps x 4 VGPR =
// 128 VGPRs). h exchanged per step as bf16 via double-buffered global hx,
// staged to LDS with XOR swizzle (byte ^= (row&7)<<4) for conflict-free
// ds_read_b64 A-fragments. h_old lives in registers (static owner mapping).
__global__ __launch_bounds__(512, 2)
void rec_kernel(const float* __restrict__ w, const float* __restrict__ scale,
                const float* __restrict__ shift, const float* __restrict__ Wu,
                float* __restrict__ hist, unsigned short* __restrict__ hx,
                unsigned int* __restrict__ cnt)
{
    __shared__ uint4 h_lds4[2048];            // 32 rows x 1024 B (512 bf16), swizzled
    char* h_lds = (char*)h_lds4;

    const int g   = blockIdx.x;               // 0..7
    const int tid = threadIdx.x;
    const int wv  = tid >> 6;                 // 0..7
    const int l   = tid & 63;
    const int c   = 4 * g + (wv >> 1);        // 0..31 col tile
    const int m   = wv & 1;                   // batch half
    const int l15 = l & 15;
    const int lg  = l >> 4;                   // 0..3
    const int jcol = 16 * c + l15;            // this lane's h/D column

    // ---- preload Wu as bf16 B-fragments ----
    // B-frag elems: j=0..3 -> k = ks*32 + lg*4 + j ; j=4..7 -> k = +16
    bf16x8 bfa[16], bfz[16];
    {
        const float* pa = Wu + (size_t)jcol * HH;
        const float* pz = Wu + (size_t)(HH + jcol) * HH;
        #pragma unroll
        for (int ks = 0; ks < 16; ++ks) {
            f32x4 a0 = *(const f32x4*)(pa + ks * 32 + lg * 4);
            f32x4 a1 = *(const f32x4*)(pa + ks * 32 + lg * 4 + 16);
            f32x4 z0 = *(const f32x4*)(pz + ks * 32 + lg * 4);
            f32x4 z1 = *(const f32x4*)(pz + ks * 32 + lg * 4 + 16);
            bf16x8 fa, fz;
            #pragma unroll
            for (int j = 0; j < 4; ++j) {
                fa[j]     = (short)f2bf(a0[j]);
                fa[4 + j] = (short)f2bf(a1[j]);
                fz[j]     = (short)f2bf(z0[j]);
                fz[4 + j] = (short)f2bf(z1[j]);
            }
            bfa[ks] = fa; bfz[ks] = fz;
        }
    }
    const float scl_a = scale[jcol],      sh_a = shift[jcol];
    const float scl_z = scale[HH + jcol], sh_z = shift[HH + jcol];

    float hold[4] = {0.f, 0.f, 0.f, 0.f};     // h_old for batches m*16+lg*4+r

    for (int i = tid; i < 2048; i += 512) h_lds4[i] = make_uint4(0, 0, 0, 0);
    __syncthreads();

    for (int t = 0; t < TT; ++t) {
        // prefetch w terms (independent of h) — latency hides under spin/gather
        float wa_[4], wz_[4];
        #pragma unroll
        for (int r = 0; r < 4; ++r) {
            const int b = m * 16 + lg * 4 + r;
            const float* wp = w + ((size_t)t * B2 + b) * G2 + jcol;
            wa_[r] = wp[0];
            wz_[r] = wp[HH];
        }

        if (t > 0) {
            if (tid == 0) {
                while (__hip_atomic_load(&cnt[t - 1], __ATOMIC_RELAXED,
                                         __HIP_MEMORY_SCOPE_AGENT) < REC_WGS)
                    __builtin_amdgcn_s_sleep(2);
                __builtin_amdgcn_fence(__ATOMIC_ACQUIRE, "agent");
            }
            __syncthreads();
            // gather prev h (bf16, 32 KB) -> LDS with XOR swizzle
            const unsigned short* src = hx + ((t - 1) & 1) * (B2 * HH);
            #pragma unroll
            for (int i = 0; i < 4; ++i) {
                const int idx = tid + i * 512;        // 16B-chunk index
                const int row = idx >> 6;
                const int ch  = idx & 63;
                uint4 v = *(const uint4*)(src + row * HH + ch * 8);
                *(uint4*)(h_lds + row * 1024 + ((ch * 16) ^ ((row & 7) << 4))) = v;
            }
            __syncthreads();
        }

        // ---- MFMA: a/z tiles over K=512 ----
        f32x4 aacc = {0.f, 0.f, 0.f, 0.f};
        f32x4 zacc = {0.f, 0.f, 0.f, 0.f};
        const int arow = m * 16 + l15;                // A row (batch)
        const char* rbase = h_lds + arow * 1024;
        const int swz = (arow & 7) << 4;
        #pragma unroll
        for (int ks = 0; ks < 16; ++ks) {
            const int off0 = ks * 64 + lg * 8;
            bf16x4 h0 = *(const bf16x4*)(rbase + (off0 ^ swz));
            bf16x4 h1 = *(const bf16x4*)(rbase + ((off0 + 32) ^ swz));
            bf16x8 af;
            af[0] = h0[0]; af[1] = h0[1]; af[2] = h0[2]; af[3] = h0[3];
            af[4] = h1[0]; af[5] = h1[1]; af[6] = h1[2]; af[7] = h1[3];
            aacc = __builtin_amdgcn_mfma_f32_16x16x32_bf16(af, bfa[ks], aacc, 0, 0, 0);
            zacc = __builtin_amdgcn_mfma_f32_16x16x32_bf16(af, bfz[ks], zacc, 0, 0, 0);
        }

        // ---- gate update + publish ----
        unsigned short* dst = hx + (t & 1) * (B2 * HH);
        #pragma unroll
        for (int r = 0; r < 4; ++r) {
            const int b = m * 16 + lg * 4 + r;
            const float aval = scl_a * wa_[r] + sh_a + aacc[r];
            const float zval = scl_z * wz_[r] + sh_z + zacc[r];
            const float zt = 1.f / (1.f + __expf(-zval));
            const float hn = zt * hold[r] + (1.f - zt) * fmaxf(aval, 0.f);
            hold[r] = hn;
            dst[b * HH + jcol] = f2bf(hn);
            hist[((size_t)t * B2 + b) * HH + jcol] = hn;
        }
        __syncthreads();   // hardware: drains vmcnt before s_barrier
        if (tid == 0) {
            __builtin_amdgcn_fence(__ATOMIC_RELEASE, "agent");
            __hip_atomic_fetch_add(&cnt[t], 1u, __ATOMIC_RELAXED,
                                   __HIP_MEMORY_SCOPE_AGENT);
        }
    }
}

// ---------------- final transpose: hist1 -> out (B,T,2H) ----------------
__global__ __launch_bounds__(256)
void out_kernel(const float* __restrict__ hist1, float* __restrict__ out)
{
    const int fi = blockIdx.x * 256 + threadIdx.x;   // float4 index
    const int flat = fi * 4;
    const int b = flat / (TT * G2);
    const int rem = flat - b * (TT * G2);
    const int t = rem >> 10;
    const int g = rem & 1023;
    float4 v;
    if (g < HH)
        v = *(const float4*)(hist1 + ((size_t)(t * B2 + b)) * HH + g);
    else
        v = *(const float4*)(hist1 + ((size_t)((TT - 1 - t) * B2 + b + 16)) * HH + (g - HH));
    *(float4*)(out + flat) = v;
}

extern "C" void kernel_launch(void* const* d_in, const int* in_sizes, int n_in,
                              void* d_out, int out_size, void* d_ws, size_t ws_size,
                              hipStream_t stream)
{
    const float* x   = (const float*)d_in[0];
    const float* Ww0 = (const float*)d_in[1];
    const float* Wu0 = (const float*)d_in[2];
    const float* g0  = (const float*)d_in[3];
    const float* b0  = (const float*)d_in[4];
    const float* Ww1 = (const float*)d_in[5];
    const float* Wu1 = (const float*)d_in[6];
    const float* g1  = (const float*)d_in[7];
    const float* b1  = (const float*)d_in[8];
    float* out = (float*)d_out;

    float* w     = (float*)d_ws;                         // 16000*1024
    float* hist0 = w + (size_t)MROWS * G2;               // 500*32*512
    float* hist1 = hist0 + (size_t)TT * B2 * HH;
    float* partS = hist1 + (size_t)TT * B2 * HH;         // 125*1024
    float* partQ = partS + 125 * G2;
    float* scale = partQ + 125 * G2;                     // 1024
    float* shift = scale + G2;
    unsigned int* cnt = (unsigned int*)(shift + G2);     // 1024 uints
    unsigned short* hx = (unsigned short*)(cnt + G2);    // 2*32*512 bf16

    const size_t needed = ((size_t)MROWS * G2 + 2 * (size_t)TT * B2 * HH +
                           2 * 125 * G2 + 2 * G2) * 4 + 4096 + 2 * B2 * HH * 2 + 4096;
    if (ws_size < needed) return;

    zero_cnt<<<4, 256, 0, stream>>>(cnt);

    // layer 0
    gemm_kernel<0><<<dim3(250, 16), 256, 0, stream>>>(x, Ww0, w);
    stats_partial<<<dim3(4, 125), 256, 0, stream>>>(w, partS, partQ);
    stats_final<<<4, 256, 0, stream>>>(partS, partQ, g0, b0, scale, shift);
    rec_kernel<<<REC_WGS, 512, 0, stream>>>(w, scale, shift, Wu0, hist0, hx, cnt);

    // layer 1
    gemm_kernel<1><<<dim3(250, 16), 256, 0, stream>>>(hist0, Ww1, w);
    stats_partial<<<dim3(4, 125), 256, 0, stream>>>(w, partS, partQ);
    stats_final<<<4, 256, 0, stream>>>(partS, partQ, g1, b1, scale, shift);
    rec_kernel<<<REC_WGS, 512, 0, stream>>>(w, scale, shift, Wu1, hist1, hx, cnt + 512);

    out_kernel<<<8000, 256, 0, stream>>>(hist1, out);
}